// Round 9
// baseline (79.707 us; speedup 1.0000x reference)
//
#include <hip/hip_runtime.h>
#include <hip/hip_bf16.h>

#define NV 512
#define NF 64

typedef __attribute__((ext_vector_type(8))) short bf16x8;
typedef __attribute__((ext_vector_type(4))) float f32x4;

union BF8 { bf16x8 v; unsigned u[4]; };

__device__ __forceinline__ unsigned short f2bf(float x) {
    unsigned u = __float_as_uint(x);
    unsigned r = (u + 0x7fffu + ((u >> 16) & 1u)) >> 16;
    return (unsigned short)r;
}

// AwT byte address: row f (1KB each); XOR-swz mixes f bits 0-2 and 3-5 so both
// staging writes (f stride 4) and GEMM reads (f stride 1) are conflict-free.
__device__ __forceinline__ unsigned awt_addr(int f, int jbyte) {
    return (unsigned)((f * 1024 + jbyte) ^ (((f ^ (f >> 3)) & 7) << 4));
}
// wT (transposed weights) in LDS: matrix m (0=w1,1=w2), row n (128B), kbyte.
__device__ __forceinline__ unsigned wt_addr(int m, int n, int kbyte) {
    return (unsigned)(m * 8192 + ((n * 128 + kbyte) ^ (((n ^ (n >> 3)) & 7) << 4)));
}

__global__ void k_edges(const int* __restrict__ ei, int E, unsigned int* __restrict__ mask) {
    int e = blockIdx.x * 256 + threadIdx.x;
    if (e < E) {
        int s = ei[e];       // src  (edge_index[0])
        int d = ei[E + e];   // dst  (edge_index[1])
        atomicOr(&mask[d * 16 + (s >> 5)], 1u << (s & 31));
    }
}

// expand bitmask -> dense bf16 adjacency (row-major [v][j]), shared by all k_main blocks
__global__ void k_adj(const unsigned int* __restrict__ mask, unsigned int* __restrict__ adj32) {
    int v = blockIdx.x;
    int t = threadIdx.x;   // 256: each thread emits one u32 = 2 bf16 (j = 2t, 2t+1)
    unsigned word = mask[v * 16 + (t >> 4)];
    unsigned pair = (word >> ((t & 15) * 2)) & 3u;
    adj32[v * 256 + t] = (pair & 1u ? 0x3F80u : 0u) | (pair & 2u ? 0x3F800000u : 0u);
}

// 4 waves per v: wave g scans mask words 4g..4g+3; 2-acc unroll; LDS reduce.
__global__ void k_S(const unsigned int* __restrict__ mask, const float* __restrict__ alpha,
                    float* __restrict__ S) {
    __shared__ float red[4][64];
    int v = blockIdx.x;
    int lane = threadIdx.x & 63;
    int g = threadIdx.x >> 6;
    float a0 = 0.f, a1 = 0.f;
    for (int wd = g * 4; wd < g * 4 + 4; ++wd) {
        unsigned bits = mask[v * 16 + wd];
        while (bits) {
            int b0 = __ffs(bits) - 1; bits &= bits - 1;
            float x0 = alpha[((size_t)v * NV + wd * 32 + b0) * NF + lane];
            if (bits) {
                int b1 = __ffs(bits) - 1; bits &= bits - 1;
                a1 += alpha[((size_t)v * NV + wd * 32 + b1) * NF + lane];
            }
            a0 += x0;
        }
    }
    red[g][lane] = a0 + a1;
    __syncthreads();
    if (g == 0)
        S[v * NF + lane] = red[0][lane] + red[1][lane] + red[2][lane] + red[3][lane];
}

// LDS (81920 B -> 2 blocks/CU):
//   [0, 65536)      AwT bf16 [64 f][512 j] swizzled; after GEMM the first 16KB
//                   is reused for w1T/w2T (staged post-barrier, acc safe in AGPRs)
//   [65536, 81920)  scr bf16 per-wave [16 rows][64], row-XOR swz, 2KB/wave
#define SCR_OFF 65536

__global__ __launch_bounds__(512, 4) void k_main(
    const float* __restrict__ alpha, const float* __restrict__ w1, const float* __restrict__ b1,
    const float* __restrict__ w2, const float* __restrict__ b2, const float* __restrict__ eps_p,
    const char* __restrict__ adjb, const float* __restrict__ S,
    float* __restrict__ out)
{
    extern __shared__ char smem[];

    const int w    = blockIdx.x;
    const int t    = threadIdx.x;
    const int lane = t & 63;
    const int wid  = t >> 6;
    const int nlo  = lane & 15;
    const int g    = lane >> 4;
    const int mbase = wid * 64;
    const float* src = alpha + (size_t)w * (NV * NF);

    // stage one half of AwT (bf16, transposed, swizzled); half i covers jb 32i..32i+31
    auto stage_half = [&](int i) {
        int task = i * 512 + t;          // 512 tasks/half: jb x fq
        int jb = task >> 4;
        int fq = task & 15;
        unsigned ua[4][4];               // [c][h] packed bf16 pairs
#pragma unroll
        for (int h = 0; h < 4; ++h) {
            f32x4 r0 = *(const f32x4*)(src + (size_t)(jb * 8 + 2 * h) * NF + fq * 4);
            f32x4 r1 = *(const f32x4*)(src + (size_t)(jb * 8 + 2 * h + 1) * NF + fq * 4);
#pragma unroll
            for (int c = 0; c < 4; ++c)
                ua[c][h] = (unsigned)f2bf(r0[c]) | ((unsigned)f2bf(r1[c]) << 16);
        }
#pragma unroll
        for (int c = 0; c < 4; ++c) {
            BF8 p;
            p.u[0] = ua[c][0]; p.u[1] = ua[c][1]; p.u[2] = ua[c][2]; p.u[3] = ua[c][3];
            *(bf16x8*)(smem + awt_addr(fq * 4 + c, jb * 16)) = p.v;
        }
    };

    f32x4 acc[4][4];

    // ---- phase 1a: stage half0 of AwT (HBM loads issue first) ----
    stage_half(0);

    // ---- phase 1b: init acc from S (C-in of first MFMA; loads hide under barrier) ----
    // C/D layout: tile (mi,nt), reg r -> row mbase+mi*16+g*4+r, col nt*16+nlo
#pragma unroll
    for (int mi = 0; mi < 4; ++mi)
#pragma unroll
        for (int nt = 0; nt < 4; ++nt)
#pragma unroll
            for (int r = 0; r < 4; ++r)
                acc[mi][nt][r] = S[(size_t)(mbase + mi * 16 + g * 4 + r) * NF + nt * 16 + nlo];

    __syncthreads();

    // adjacency GEMM over one kq (4 K-steps); A-frags loaded directly from the
    // precomputed L2-resident adj_bf16 (phi: elem e -> k = kk*32 + g*8 + e, row = nlo)
    auto gemm_q = [&](int kq) {
#pragma unroll
        for (int kr = 0; kr < 4; ++kr) {
            const int kk = kq * 4 + kr;
            bf16x8 afr[4];
#pragma unroll
            for (int mi = 0; mi < 4; ++mi)
                afr[mi] = *(const bf16x8*)(adjb + ((size_t)(mbase + mi * 16 + nlo) << 10) + kk * 64 + g * 16);
#pragma unroll
            for (int nt = 0; nt < 4; ++nt) {
                bf16x8 bfr = *(const bf16x8*)(smem + awt_addr(nt * 16 + nlo, kk * 64 + g * 16));
#pragma unroll
                for (int mi = 0; mi < 4; ++mi)
                    acc[mi][nt] = __builtin_amdgcn_mfma_f32_16x16x32_bf16(afr[mi], bfr, acc[mi][nt], 0, 0, 0);
            }
        }
    };

    // ---- pipeline: {stage half1 || GEMM kq0-1 (half0)} | barrier | GEMM kq2-3 ----
    stage_half(1);            // writes jbyte >=512: disjoint from kq0-1 reads
    gemm_q(0);
    gemm_q(1);
    __syncthreads();
    gemm_q(2);
    gemm_q(3);
    __syncthreads();          // all AwT reads complete

    // ---- stage w1T/w2T into first 16KB (AwT region now dead) ----
    if (t < 256) {
        int m  = t >> 7;
        int sub = t & 127;
        int jb = sub >> 4;
        int fq = sub & 15;
        const float* wsrc = m ? w2 : w1;
        unsigned ua[4][4];
#pragma unroll
        for (int h = 0; h < 4; ++h) {
            f32x4 r0 = *(const f32x4*)(wsrc + (size_t)(jb * 8 + 2 * h) * NF + fq * 4);
            f32x4 r1 = *(const f32x4*)(wsrc + (size_t)(jb * 8 + 2 * h + 1) * NF + fq * 4);
#pragma unroll
            for (int c = 0; c < 4; ++c)
                ua[c][h] = (unsigned)f2bf(r0[c]) | ((unsigned)f2bf(r1[c]) << 16);
        }
#pragma unroll
        for (int c = 0; c < 4; ++c) {
            BF8 p;
            p.u[0] = ua[c][0]; p.u[1] = ua[c][1]; p.u[2] = ua[c][2]; p.u[3] = ua[c][3];
            *(bf16x8*)(smem + wt_addr(m, fq * 4 + c, jb * 16)) = p.v;
        }
    }
    float b1v[4], b2v[4];
#pragma unroll
    for (int nt = 0; nt < 4; ++nt) {
        b1v[nt] = b1[nt * 16 + nlo];
        b2v[nt] = b2[nt * 16 + nlo];
    }
    const float ceps = 1.0f + eps_p[0];

    __syncthreads();

    // ---- epilogue per m-tile (S already in acc; rv loads grouped up front) ----
    char* myscr = smem + SCR_OFF + wid * 2048;   // [16][64] bf16, row 128B, XOR swz
#pragma unroll
    for (int mi = 0; mi < 4; ++mi) {
        int v0 = mbase + mi * 16;

        float rvv[4][4];   // [nt][r] residual, issued as one load batch
#pragma unroll
        for (int nt = 0; nt < 4; ++nt)
#pragma unroll
            for (int r = 0; r < 4; ++r)
                rvv[nt][r] = alpha[((size_t)(v0 + g * 4 + r) * NV + w) * NF + nt * 16 + nlo];

#pragma unroll
        for (int nt = 0; nt < 4; ++nt) {
            int f = nt * 16 + nlo;
#pragma unroll
            for (int r = 0; r < 4; ++r) {
                float pre = acc[mi][nt][r] + ceps * rvv[nt][r];
                int row = g * 4 + r;
                *(unsigned short*)(myscr + row * 128 + ((2 * f) ^ ((row & 7) << 4))) = f2bf(pre);
            }
        }

        // layer 1  (A: row nlo, k-bytes g*16 + ks*64, row-XOR swz; B from LDS wT)
        bf16x8 a0 = *(const bf16x8*)(myscr + nlo * 128 + ((g * 16) ^ ((nlo & 7) << 4)));
        bf16x8 a1 = *(const bf16x8*)(myscr + nlo * 128 + ((g * 16 + 64) ^ ((nlo & 7) << 4)));
        f32x4 accm[4];
#pragma unroll
        for (int nt = 0; nt < 4; ++nt) {
            bf16x8 wf0 = *(const bf16x8*)(smem + wt_addr(0, nt * 16 + nlo, g * 16));
            bf16x8 wf1 = *(const bf16x8*)(smem + wt_addr(0, nt * 16 + nlo, 64 + g * 16));
            f32x4 z = {0.f, 0.f, 0.f, 0.f};
            z = __builtin_amdgcn_mfma_f32_16x16x32_bf16(a0, wf0, z, 0, 0, 0);
            z = __builtin_amdgcn_mfma_f32_16x16x32_bf16(a1, wf1, z, 0, 0, 0);
            accm[nt] = z;
        }

        // relu + b1 -> scr (C/D: row=(l>>4)*4+r, col=nt*16+(l&15))
#pragma unroll
        for (int nt = 0; nt < 4; ++nt)
#pragma unroll
            for (int r = 0; r < 4; ++r) {
                float hv = accm[nt][r] + b1v[nt];
                hv = hv > 0.f ? hv : 0.f;
                int row = g * 4 + r;
                *(unsigned short*)(myscr + row * 128 + ((2 * (nt * 16 + nlo)) ^ ((row & 7) << 4))) = f2bf(hv);
            }

        // layer 2
        bf16x8 h0 = *(const bf16x8*)(myscr + nlo * 128 + ((g * 16) ^ ((nlo & 7) << 4)));
        bf16x8 h1 = *(const bf16x8*)(myscr + nlo * 128 + ((g * 16 + 64) ^ ((nlo & 7) << 4)));
#pragma unroll
        for (int nt = 0; nt < 4; ++nt) {
            bf16x8 wf0 = *(const bf16x8*)(smem + wt_addr(1, nt * 16 + nlo, g * 16));
            bf16x8 wf1 = *(const bf16x8*)(smem + wt_addr(1, nt * 16 + nlo, 64 + g * 16));
            f32x4 z = {0.f, 0.f, 0.f, 0.f};
            z = __builtin_amdgcn_mfma_f32_16x16x32_bf16(h0, wf0, z, 0, 0, 0);
            z = __builtin_amdgcn_mfma_f32_16x16x32_bf16(h1, wf1, z, 0, 0, 0);
#pragma unroll
            for (int r = 0; r < 4; ++r) {
                int vv = v0 + g * 4 + r;
                out[((size_t)vv * NV + w) * NF + nt * 16 + nlo] = z[r] + b2v[nt];
            }
        }
    }
}

extern "C" void kernel_launch(void* const* d_in, const int* in_sizes, int n_in,
                              void* d_out, int out_size, void* d_ws, size_t ws_size,
                              hipStream_t stream) {
    const float* alpha = (const float*)d_in[0];
    const int*   ei    = (const int*)d_in[1];
    const float* w1    = (const float*)d_in[2];
    const float* b1    = (const float*)d_in[3];
    const float* w2    = (const float*)d_in[4];
    const float* b2    = (const float*)d_in[5];
    const float* eps   = (const float*)d_in[6];
    float* out = (float*)d_out;
    int E = in_sizes[1] / 2;

    // ws layout (u32 units): mask[8192] | S[512*64 f32] | adj32[512*256]
    unsigned int* mask  = (unsigned int*)d_ws;
    float*        S     = (float*)d_ws + 8192;
    unsigned int* adj32 = (unsigned int*)d_ws + 8192 + 512 * 64;

    hipMemsetAsync(mask, 0, 8192 * sizeof(unsigned int), stream);
    k_edges<<<(E + 255) / 256, 256, 0, stream>>>(ei, E, mask);
    k_adj  <<<NV, 256, 0, stream>>>(mask, adj32);
    k_S    <<<NV, 256, 0, stream>>>(mask, alpha, S);

    const int smem_bytes = 81920;   // 64K AwT(+wT reuse) + 16K scr -> 2 blocks/CU
    hipFuncSetAttribute(reinterpret_cast<const void*>(k_main),
                        hipFuncAttributeMaxDynamicSharedMemorySize, smem_bytes);
    k_main <<<NV, 512, smem_bytes, stream>>>(alpha, w1, b1, w2, b2, eps,
                                             (const char*)adj32, S, out);
}

// Round 10
// 65.498 us; speedup vs baseline: 1.2169x; 1.2169x over previous
//
#include <hip/hip_runtime.h>
#include <hip/hip_bf16.h>

#define NV 512
#define NF 64

typedef __attribute__((ext_vector_type(8))) short bf16x8;
typedef __attribute__((ext_vector_type(4))) float f32x4;

union BF8 { bf16x8 v; unsigned u[4]; };

__device__ __forceinline__ unsigned short f2bf(float x) {
    unsigned u = __float_as_uint(x);
    unsigned r = (u + 0x7fffu + ((u >> 16) & 1u)) >> 16;
    return (unsigned short)r;
}

// AwT byte address: row f (1KB each); XOR-swz mixes f bits 0-2 and 3-5 so both
// staging writes (f stride 4) and GEMM reads (f stride 1) are conflict-free.
__device__ __forceinline__ unsigned awt_addr(int f, int jbyte) {
    return (unsigned)((f * 1024 + jbyte) ^ (((f ^ (f >> 3)) & 7) << 4));
}
// wT (transposed weights) in LDS: matrix m (0=w1,1=w2), row n (128B), kbyte.
__device__ __forceinline__ unsigned wt_addr(int m, int n, int kbyte) {
    return (unsigned)(m * 8192 + ((n * 128 + kbyte) ^ (((n ^ (n >> 3)) & 7) << 4)));
}
// scr slot: injective on {r,r+4,r+8,r+12} (epilogue write groups) and
// 2-per-slot over 16 rows (reads) -> ~min aliasing both ways.
__device__ __forceinline__ int scr_slot(int row) {
    return ((row >> 2) ^ ((row & 3) << 1)) & 7;
}

__global__ void k_edges(const int* __restrict__ ei, int E, unsigned int* __restrict__ mask) {
    int e = blockIdx.x * 256 + threadIdx.x;
    if (e < E) {
        int s = ei[e];       // src  (edge_index[0])
        int d = ei[E + e];   // dst  (edge_index[1])
        atomicOr(&mask[d * 16 + (s >> 5)], 1u << (s & 31));
    }
}

// 4 waves per v: wave g scans mask words 4g..4g+3; 2-acc unroll; LDS reduce.
__global__ void k_S(const unsigned int* __restrict__ mask, const float* __restrict__ alpha,
                    float* __restrict__ S) {
    __shared__ float red[4][64];
    int v = blockIdx.x;
    int lane = threadIdx.x & 63;
    int g = threadIdx.x >> 6;
    float a0 = 0.f, a1 = 0.f;
    for (int wd = g * 4; wd < g * 4 + 4; ++wd) {
        unsigned bits = mask[v * 16 + wd];
        while (bits) {
            int b0 = __ffs(bits) - 1; bits &= bits - 1;
            float x0 = alpha[((size_t)v * NV + wd * 32 + b0) * NF + lane];
            if (bits) {
                int b1 = __ffs(bits) - 1; bits &= bits - 1;
                a1 += alpha[((size_t)v * NV + wd * 32 + b1) * NF + lane];
            }
            a0 += x0;
        }
    }
    red[g][lane] = a0 + a1;
    __syncthreads();
    if (g == 0)
        S[v * NF + lane] = red[0][lane] + red[1][lane] + red[2][lane] + red[3][lane];
}

// LDS (65536 B -> 2 blocks/CU with headroom):
//   [0, 65536)  AwT bf16 [64 f][512 j] swizzled (GEMM phase).
//   After the post-GEMM barrier the region is dead and is reused:
//     [0, 16384)       w1T/w2T
//     [16384, 32768)   scr bf16 per-wave [16 rows][64], 2KB/wave, scr_slot swz

__global__ __launch_bounds__(512, 4) void k_main(
    const float* __restrict__ alpha, const float* __restrict__ w1, const float* __restrict__ b1,
    const float* __restrict__ w2, const float* __restrict__ b2, const float* __restrict__ eps_p,
    const unsigned int* __restrict__ mask, const float* __restrict__ S,
    float* __restrict__ out)
{
    extern __shared__ char smem[];

    const int w    = blockIdx.x;
    const int t    = threadIdx.x;
    const int lane = t & 63;
    const int wid  = t >> 6;
    const int nlo  = lane & 15;
    const int g    = lane >> 4;
    const int mbase = wid * 64;
    const float* src = alpha + (size_t)w * (NV * NF);

    // stage one half of AwT (bf16, transposed, swizzled); half i covers jb 32i..32i+31
    auto stage_half = [&](int i) {
        int task = i * 512 + t;          // 512 tasks/half: jb x fq
        int jb = task >> 4;
        int fq = task & 15;
        unsigned ua[4][4];               // [c][h] packed bf16 pairs
#pragma unroll
        for (int h = 0; h < 4; ++h) {
            f32x4 r0 = *(const f32x4*)(src + (size_t)(jb * 8 + 2 * h) * NF + fq * 4);
            f32x4 r1 = *(const f32x4*)(src + (size_t)(jb * 8 + 2 * h + 1) * NF + fq * 4);
#pragma unroll
            for (int c = 0; c < 4; ++c)
                ua[c][h] = (unsigned)f2bf(r0[c]) | ((unsigned)f2bf(r1[c]) << 16);
        }
#pragma unroll
        for (int c = 0; c < 4; ++c) {
            BF8 p;
            p.u[0] = ua[c][0]; p.u[1] = ua[c][1]; p.u[2] = ua[c][2]; p.u[3] = ua[c][3];
            *(bf16x8*)(smem + awt_addr(fq * 4 + c, jb * 16)) = p.v;
        }
    };

    f32x4 acc[4][4];

    // ---- phase 1a: stage half0 of AwT (HBM loads issue first) ----
    stage_half(0);

    // ---- phase 1b: init acc from S (C-in of first MFMA; loads hide under barrier) ----
    // C/D layout: tile (mi,nt), reg r -> row mbase+mi*16+g*4+r, col nt*16+nlo
#pragma unroll
    for (int mi = 0; mi < 4; ++mi)
#pragma unroll
        for (int nt = 0; nt < 4; ++nt)
#pragma unroll
            for (int r = 0; r < 4; ++r)
                acc[mi][nt][r] = S[(size_t)(mbase + mi * 16 + g * 4 + r) * NF + nt * 16 + nlo];

    __syncthreads();

    // adjacency GEMM over one kq (4 K-steps); mask words via one dwordx4 per (mi,kq),
    // A-frags expanded from bits in-register (VALU overlaps MFMA/LDS)
    auto gemm_q = [&](int kq) {
        unsigned qw[4][4];
#pragma unroll
        for (int mi = 0; mi < 4; ++mi) {
            const uint4 q = *(const uint4*)(mask + (size_t)(mbase + mi * 16 + nlo) * 16 + kq * 4);
            qw[mi][0] = q.x; qw[mi][1] = q.y; qw[mi][2] = q.z; qw[mi][3] = q.w;
        }
#pragma unroll
        for (int kr = 0; kr < 4; ++kr) {
            const int kk = kq * 4 + kr;
            BF8 afr[4];
#pragma unroll
            for (int mi = 0; mi < 4; ++mi) {
                unsigned byteb = (qw[mi][kr] >> (g * 8)) & 0xFFu;
#pragma unroll
                for (int h = 0; h < 4; ++h) {
                    unsigned b0 = (byteb >> (2 * h)) & 1u;
                    unsigned b1 = (byteb >> (2 * h + 1)) & 1u;
                    afr[mi].u[h] = (b0 ? 0x3F80u : 0u) | (b1 ? 0x3F800000u : 0u);
                }
            }
#pragma unroll
            for (int nt = 0; nt < 4; ++nt) {
                bf16x8 bfr = *(const bf16x8*)(smem + awt_addr(nt * 16 + nlo, kk * 64 + g * 16));
#pragma unroll
                for (int mi = 0; mi < 4; ++mi)
                    acc[mi][nt] = __builtin_amdgcn_mfma_f32_16x16x32_bf16(afr[mi].v, bfr, acc[mi][nt], 0, 0, 0);
            }
        }
    };

    // ---- pipeline: {stage half1 || GEMM kq0-1 (half0)} | barrier | GEMM kq2-3 ----
    stage_half(1);            // writes jbyte >=512: disjoint from kq0-1 reads
    gemm_q(0);
    gemm_q(1);
    __syncthreads();
    gemm_q(2);
    gemm_q(3);
    __syncthreads();          // all AwT reads complete; region reusable

    // ---- stage w1T/w2T into first 16KB ----
    if (t < 256) {
        int m  = t >> 7;
        int sub = t & 127;
        int jb = sub >> 4;
        int fq = sub & 15;
        const float* wsrc = m ? w2 : w1;
        unsigned ua[4][4];
#pragma unroll
        for (int h = 0; h < 4; ++h) {
            f32x4 r0 = *(const f32x4*)(wsrc + (size_t)(jb * 8 + 2 * h) * NF + fq * 4);
            f32x4 r1 = *(const f32x4*)(wsrc + (size_t)(jb * 8 + 2 * h + 1) * NF + fq * 4);
#pragma unroll
            for (int c = 0; c < 4; ++c)
                ua[c][h] = (unsigned)f2bf(r0[c]) | ((unsigned)f2bf(r1[c]) << 16);
        }
#pragma unroll
        for (int c = 0; c < 4; ++c) {
            BF8 p;
            p.u[0] = ua[c][0]; p.u[1] = ua[c][1]; p.u[2] = ua[c][2]; p.u[3] = ua[c][3];
            *(bf16x8*)(smem + wt_addr(m, fq * 4 + c, jb * 16)) = p.v;
        }
    }
    float b1v[4], b2v[4];
#pragma unroll
    for (int nt = 0; nt < 4; ++nt) {
        b1v[nt] = b1[nt * 16 + nlo];
        b2v[nt] = b2[nt * 16 + nlo];
    }
    const float ceps = 1.0f + eps_p[0];

    // prefetch mi=0 residual before the barrier (hides under wT staging wait)
    float rvv[4][4];
#pragma unroll
    for (int nt = 0; nt < 4; ++nt)
#pragma unroll
        for (int r = 0; r < 4; ++r)
            rvv[nt][r] = alpha[((size_t)(mbase + g * 4 + r) * NV + w) * NF + nt * 16 + nlo];

    __syncthreads();

    // ---- epilogue per m-tile (rv prefetched one tile ahead) ----
    char* myscr = smem + 16384 + wid * 2048;   // [16][64] bf16, scr_slot swz
#pragma unroll
    for (int mi = 0; mi < 4; ++mi) {
        int v0 = mbase + mi * 16;

        float rvc[4][4];
#pragma unroll
        for (int nt = 0; nt < 4; ++nt)
#pragma unroll
            for (int r = 0; r < 4; ++r) rvc[nt][r] = rvv[nt][r];

        if (mi < 3) {   // prefetch next tile's residual
#pragma unroll
            for (int nt = 0; nt < 4; ++nt)
#pragma unroll
                for (int r = 0; r < 4; ++r)
                    rvv[nt][r] = alpha[((size_t)(v0 + 16 + g * 4 + r) * NV + w) * NF + nt * 16 + nlo];
        }

#pragma unroll
        for (int nt = 0; nt < 4; ++nt) {
            int f = nt * 16 + nlo;
#pragma unroll
            for (int r = 0; r < 4; ++r) {
                float pre = acc[mi][nt][r] + ceps * rvc[nt][r];
                int row = g * 4 + r;
                *(unsigned short*)(myscr + row * 128 + ((2 * f) ^ (scr_slot(row) << 4))) = f2bf(pre);
            }
        }

        // layer 1  (A: row nlo, k-bytes g*16 + ks*64, slot swz; B from LDS wT)
        bf16x8 a0 = *(const bf16x8*)(myscr + nlo * 128 + ((g * 16) ^ (scr_slot(nlo) << 4)));
        bf16x8 a1 = *(const bf16x8*)(myscr + nlo * 128 + ((g * 16 + 64) ^ (scr_slot(nlo) << 4)));
        f32x4 accm[4];
#pragma unroll
        for (int nt = 0; nt < 4; ++nt) {
            bf16x8 wf0 = *(const bf16x8*)(smem + wt_addr(0, nt * 16 + nlo, g * 16));
            bf16x8 wf1 = *(const bf16x8*)(smem + wt_addr(0, nt * 16 + nlo, 64 + g * 16));
            f32x4 z = {0.f, 0.f, 0.f, 0.f};
            z = __builtin_amdgcn_mfma_f32_16x16x32_bf16(a0, wf0, z, 0, 0, 0);
            z = __builtin_amdgcn_mfma_f32_16x16x32_bf16(a1, wf1, z, 0, 0, 0);
            accm[nt] = z;
        }

        // relu + b1 -> scr (C/D: row=(l>>4)*4+r, col=nt*16+(l&15))
#pragma unroll
        for (int nt = 0; nt < 4; ++nt)
#pragma unroll
            for (int r = 0; r < 4; ++r) {
                float hv = accm[nt][r] + b1v[nt];
                hv = hv > 0.f ? hv : 0.f;
                int row = g * 4 + r;
                *(unsigned short*)(myscr + row * 128 + ((2 * (nt * 16 + nlo)) ^ (scr_slot(row) << 4))) = f2bf(hv);
            }

        // layer 2
        bf16x8 h0 = *(const bf16x8*)(myscr + nlo * 128 + ((g * 16) ^ (scr_slot(nlo) << 4)));
        bf16x8 h1 = *(const bf16x8*)(myscr + nlo * 128 + ((g * 16 + 64) ^ (scr_slot(nlo) << 4)));
#pragma unroll
        for (int nt = 0; nt < 4; ++nt) {
            bf16x8 wf0 = *(const bf16x8*)(smem + wt_addr(1, nt * 16 + nlo, g * 16));
            bf16x8 wf1 = *(const bf16x8*)(smem + wt_addr(1, nt * 16 + nlo, 64 + g * 16));
            f32x4 z = {0.f, 0.f, 0.f, 0.f};
            z = __builtin_amdgcn_mfma_f32_16x16x32_bf16(h0, wf0, z, 0, 0, 0);
            z = __builtin_amdgcn_mfma_f32_16x16x32_bf16(h1, wf1, z, 0, 0, 0);
#pragma unroll
            for (int r = 0; r < 4; ++r) {
                int vv = v0 + g * 4 + r;
                out[((size_t)vv * NV + w) * NF + nt * 16 + nlo] = z[r] + b2v[nt];
            }
        }
    }
}

extern "C" void kernel_launch(void* const* d_in, const int* in_sizes, int n_in,
                              void* d_out, int out_size, void* d_ws, size_t ws_size,
                              hipStream_t stream) {
    const float* alpha = (const float*)d_in[0];
    const int*   ei    = (const int*)d_in[1];
    const float* w1    = (const float*)d_in[2];
    const float* b1    = (const float*)d_in[3];
    const float* w2    = (const float*)d_in[4];
    const float* b2    = (const float*)d_in[5];
    const float* eps   = (const float*)d_in[6];
    float* out = (float*)d_out;
    int E = in_sizes[1] / 2;

    // ws layout (u32/f32 units): mask[8192] | S[512*64]
    unsigned int* mask = (unsigned int*)d_ws;
    float* S = (float*)d_ws + 8192;

    hipMemsetAsync(mask, 0, 8192 * sizeof(unsigned int), stream);
    k_edges<<<(E + 255) / 256, 256, 0, stream>>>(ei, E, mask);
    k_S    <<<NV, 256, 0, stream>>>(mask, alpha, S);

    const int smem_bytes = 65536;   // AwT (reused for wT+scr post-GEMM)
    hipFuncSetAttribute(reinterpret_cast<const void*>(k_main),
                        hipFuncAttributeMaxDynamicSharedMemorySize, smem_bytes);
    k_main <<<NV, 512, smem_bytes, stream>>>(alpha, w1, b1, w2, b2, eps, mask, S, out);
}